// Round 8
// baseline (1668.320 us; speedup 1.0000x reference)
//
#include <hip/hip_runtime.h>

// ---------------- problem constants ----------------
#define B_RUNS 500
#define WAYS   5
#define NSUP   25
#define NQ     75
#define NN     100
#define DIM    640
#define TOPK   6
#define KHOP   4
#define NEPOCH 10

// ---------------- barrier control region ----------------
#define CTRL_BYTES 262144
#define KB2    250                // k2 blocks (2 episodes each)
#define NBK    25                 // buckets
#define BPB    10                 // blocks per bucket (250/25)
#define NROUND 512
#define READYB 0x80000000u

// per-episode FLOATS: Gf [10000] f32 | Inv [10000] f32
#define EP_FLT   20224
#define GF_OFF   0
#define INV_OFF  10000

// k1 LDS: G (f32, stride 101), staging overlaid. ~49 KB total with
// statics -> 3 blocks/CU by LDS; grid (500x8 waves) is the occupancy cap.
#define GS   101
#define DYN_LDS_BYTES (NN * GS * 4)          // 40400 B

#if defined(__has_builtin)
#if __has_builtin(__builtin_amdgcn_permlane32_swap)
#define HAVE_PLSWAP 1
#endif
#endif

// ---------------- fast wave-64 f32 helpers ----------------
template <int CTRL>
__device__ __forceinline__ float dpp_addf(float v) {
  int r = __builtin_amdgcn_update_dpp(0, __float_as_int(v), CTRL, 0xF, 0xF, false);
  return v + __int_as_float(r);
}
template <int PAT>
__device__ __forceinline__ float swz_addf(float v) {
  return v + __int_as_float(__builtin_amdgcn_ds_swizzle(__float_as_int(v), PAT));
}
__device__ __forceinline__ float swap32_addf(float v) {
#ifdef HAVE_PLSWAP
  int x = __float_as_int(v);
  auto r = __builtin_amdgcn_permlane32_swap(x, x, false, false);
  return __int_as_float(r[0]) + __int_as_float(r[1]);
#else
  return v + __shfl_xor(v, 32, 64);
#endif
}
// full 64-lane f32 sum, result uniform across lanes
__device__ __forceinline__ float wsum64f_fast(float v) {
  v = dpp_addf<0x121>(v);    // row_ror:1
  v = dpp_addf<0x122>(v);    // row_ror:2
  v = dpp_addf<0x124>(v);    // row_ror:4
  v = dpp_addf<0x128>(v);    // row_ror:8
  v = swz_addf<0x401F>(v);   // xor 16
  v = swap32_addf(v);        // xor 32
  return __int_as_float(__builtin_amdgcn_readfirstlane(__float_as_int(v)));
}
// fast f32 reciprocal: hw rcp + 1 Newton
__device__ __forceinline__ float frcpf(float x) {
#if __has_builtin(__builtin_amdgcn_rcpf)
  float r = __builtin_amdgcn_rcpf(x);
#else
  float r = 1.0f / x;
#endif
  float e = fmaf(-x, r, 1.0f);
  r = fmaf(r, e, r);
  return r;
}

// 2-level grid barrier + global max of payload, hierarchical release.
__device__ unsigned grid_barrier_max(unsigned* ctrlu, int b, unsigned rnd, unsigned lm) {
  unsigned r = rnd < (NROUND - 1) ? rnd : (NROUND - 1);
  const int bk = b % NBK;
  unsigned* barr  = ctrlu + bk * NROUND + r;
  unsigned* bmax  = ctrlu + (NBK + bk) * NROUND + r;
  unsigned* marr  = ctrlu + 2 * NBK * NROUND + r;
  unsigned* mmax  = ctrlu + 2 * NBK * NROUND + NROUND + r;
  unsigned* bflag = ctrlu + (2 * NBK + 2) * NROUND + bk * NROUND + r;

  __hip_atomic_fetch_max(bmax, lm, __ATOMIC_RELAXED, __HIP_MEMORY_SCOPE_AGENT);
  unsigned a = __hip_atomic_fetch_add(barr, 1u, __ATOMIC_ACQ_REL, __HIP_MEMORY_SCOPE_AGENT);
  long sp = 0;
  if (a == (unsigned)(BPB - 1)) {
    unsigned bm = __hip_atomic_load(bmax, __ATOMIC_RELAXED, __HIP_MEMORY_SCOPE_AGENT);
    __hip_atomic_fetch_max(mmax, bm, __ATOMIC_RELAXED, __HIP_MEMORY_SCOPE_AGENT);
    __hip_atomic_fetch_add(marr, 1u, __ATOMIC_ACQ_REL, __HIP_MEMORY_SCOPE_AGENT);
    while (__hip_atomic_load(marr, __ATOMIC_RELAXED, __HIP_MEMORY_SCOPE_AGENT) < (unsigned)NBK) {
      __builtin_amdgcn_s_sleep(2);
      if (++sp > 50000000L) break;   // safety: terminate, don't hang
    }
    __builtin_amdgcn_fence(__ATOMIC_ACQUIRE, "agent");
    unsigned g = __hip_atomic_load(mmax, __ATOMIC_RELAXED, __HIP_MEMORY_SCOPE_AGENT);
    __hip_atomic_store(bflag, g | READYB, __ATOMIC_RELEASE, __HIP_MEMORY_SCOPE_AGENT);
    return g;
  } else {
    unsigned f;
    while (!((f = __hip_atomic_load(bflag, __ATOMIC_RELAXED, __HIP_MEMORY_SCOPE_AGENT)) & READYB)) {
      __builtin_amdgcn_s_sleep(4);
      if (++sp > 50000000L) break;   // safety: terminate, don't hang
    }
    __builtin_amdgcn_fence(__ATOMIC_ACQUIRE, "agent");
    return f & ~READYB;
  }
}

// =====================================================================
// Kernel 1 (gram-space), f32, 512 threads (8 waves). Gram: 16x32 grid,
// 7x4 tile, float4 staged loads/reads (quad-of-k layout, ascending k ->
// bit-identical). Per hop: top-6 -> sparse L -> in-place congruence.
// Hop 3: Gf, dense L^2, W chain, M = I-0.7W, GJ inverse with SINGLE
// barrier per k (next pivot row/col captured during the update) -> Inv.
// =====================================================================
__global__ __launch_bounds__(512, 6) void k1_lds(const float* __restrict__ xs,
                                                 const float* __restrict__ xq,
                                                 char* __restrict__ wsb) {
  extern __shared__ float dynf[];
  float* G   = dynf;                  // 100 x 101 (padded stride)
  float* STf = dynf;                  // staging overlay (gram phase only)

  const int b = blockIdx.x;
  float* GfF  = (float*)(wsb + CTRL_BYTES) + (size_t)b * EP_FLT;
  float* InvF = GfF + INV_OFF;

  __shared__ float nsh[NN], Dsh[NN];
  __shared__ float rowkA[NN], colkA[NN], rowkB[NN], colkB[NN];
  __shared__ float wS[NN][7];
  __shared__ int   idxS[NN][7];
  __shared__ int   cntS[NN];

  const int t  = threadIdx.x;

  // ---- initial gram G0 = F F^T (16x32 grid, 7x4 tile, f32x4 LDS) ----
  {
    const int tx = t & 31;            // col group 0..31
    const int ty = t >> 5;            // row group 0..15
    int ia[7], ja[4];
    #pragma unroll
    for (int a = 0; a < 7; ++a) { int v = ty + 16 * a; ia[a] = v < NN ? v : NN - 1; }
    #pragma unroll
    for (int c = 0; c < 4; ++c) { int v = tx + 32 * c; ja[c] = v < NN ? v : NN - 1; }

    float acc[7][4];
    #pragma unroll
    for (int a = 0; a < 7; ++a)
      #pragma unroll
      for (int c = 0; c < 4; ++c) acc[a][c] = 0.0f;
    const float* xsb = xs + (size_t)b * NSUP * DIM;
    const float* xqb = xq + (size_t)b * NQ * DIM;
    for (int chunk = 0; chunk < 40; ++chunk) {
      int k0 = chunk * 16;
      // stage 100 rows x 16 k as 4 quads: STf[q*404 + 4r + m], float4 I/O
      if (t < 400) {
        int r = t >> 2, kq = t & 3;
        const float* src = (r < NSUP) ? (xsb + r * DIM + k0 + 4 * kq)
                                      : (xqb + (r - NSUP) * DIM + k0 + 4 * kq);
        float4 v = *(const float4*)src;
        *(float4*)(STf + kq * 404 + 4 * r) = v;
      }
      __syncthreads();
      #pragma unroll 1
      for (int q = 0; q < 4; ++q) {
        float4 rv[7], cv[4];
        #pragma unroll
        for (int a = 0; a < 7; ++a) rv[a] = *(const float4*)(STf + q * 404 + 4 * ia[a]);
        #pragma unroll
        for (int c = 0; c < 4; ++c) cv[c] = *(const float4*)(STf + q * 404 + 4 * ja[c]);
        #pragma unroll
        for (int a = 0; a < 7; ++a)
          #pragma unroll
          for (int c = 0; c < 4; ++c) {
            acc[a][c] = fmaf(rv[a].x, cv[c].x, acc[a][c]);
            acc[a][c] = fmaf(rv[a].y, cv[c].y, acc[a][c]);
            acc[a][c] = fmaf(rv[a].z, cv[c].z, acc[a][c]);
            acc[a][c] = fmaf(rv[a].w, cv[c].w, acc[a][c]);
          }
      }
      __syncthreads();
    }
    // staging dead from here; G overlays it
    #pragma unroll
    for (int a = 0; a < 7; ++a)
      #pragma unroll
      for (int c = 0; c < 4; ++c) {
        int i = ty + 16 * a, j = tx + 32 * c;
        if (i < NN && j < NN) G[i * GS + j] = acc[a][c];
      }
    __syncthreads();
  }

  for (int hop = 0; hop < KHOP; ++hop) {
    if (t < NN) nsh[t] = G[t * GS + t];
    __syncthreads();
    // ---- top-6 per row by clamped distance (ascending; ties -> lowest index) ----
    int kj[TOPK]; float ke[TOPK];
    if (t < NN) {
      unsigned long long m0 = 0ull, m1 = 0ull;
      const float nt = nsh[t];
      for (int s = 0; s < TOPK; ++s) {
        float best = 3.0e38f; int bj = 0;
        for (int j = 0; j < NN; ++j) {
          unsigned long long bit = (j < 64) ? ((m0 >> j) & 1ull) : ((m1 >> (j - 64)) & 1ull);
          if (bit) continue;
          float d = (nt + nsh[j]) - 2.0f * G[t * GS + j];
          d = d > 0.0f ? d : 0.0f;
          if (d < best) { best = d; bj = j; }     // strict <: lowest index wins ties
        }
        if (bj < 64) m0 |= 1ull << bj; else m1 |= 1ull << (bj - 64);
      }
      float s = 0.0f;
      unsigned long long mm0 = m0, mm1 = m1;
      #pragma unroll
      for (int sidx = 0; sidx < TOPK; ++sidx) {
        int j;
        if (mm0) { j = __ffsll((long long)mm0) - 1; mm0 &= mm0 - 1; }
        else     { j = 64 + __ffsll((long long)mm1) - 1; mm1 &= mm1 - 1; }
        float d = (nt + nsh[j]) - 2.0f * G[t * GS + j];
        d = d > 0.0f ? d : 0.0f;
        float e = expf(-10.0f * d);
        kj[sidx] = j; ke[sidx] = e;
        s += e;
      }
      Dsh[t] = 1.0f / sqrtf(s);
    }
    __syncthreads();
    // ---- build sparse L row: ascending index, self 0.5 folded/inserted ----
    if (t < NN) {
      int cnt = 0; bool sd = false;
      float dt = Dsh[t];
      #pragma unroll
      for (int sidx = 0; sidx < TOPK; ++sidx) {
        int j = kj[sidx];
        float lw = 0.5f * ((Dsh[j] * ke[sidx]) * dt);
        if (j == t) { lw = 0.5f + lw; sd = true; }
        else if (!sd && j > t) { idxS[t][cnt] = t; wS[t][cnt] = 0.5f; ++cnt; sd = true; }
        idxS[t][cnt] = j; wS[t][cnt] = lw; ++cnt;
      }
      if (!sd) { idxS[t][cnt] = t; wS[t][cnt] = 0.5f; ++cnt; }
      cntS[t] = cnt;
    }
    __syncthreads();

    // ---- congruence: G <- L (L G L^T) L^T, fully in-place in LDS ----
    {
      const int wv8 = t >> 6, ln = t & 63;
      const int i2 = ln + 64;
      const bool h2 = (i2 < NN);
      const int r1 = h2 ? i2 : 0;
      float lw0[7], lw1[7]; int li0[7], li1[7];
      {
        int c0 = cntS[ln];
        int c1 = h2 ? cntS[r1] : 0;
        #pragma unroll
        for (int s2 = 0; s2 < 7; ++s2) {
          lw0[s2] = (s2 < c0) ? wS[ln][s2] : 0.0f;
          li0[s2] = (s2 < c0) ? idxS[ln][s2] : 0;
          lw1[s2] = (s2 < c1) ? wS[r1][s2] : 0.0f;
          li1[s2] = (s2 < c1) ? idxS[r1][s2] : 0;
        }
      }
      #pragma unroll 1
      for (int pair = 0; pair < 2; ++pair) {
        // G <- L * G : per COLUMN (one wave per column), in place.
        for (int c = wv8; c < NN; c += 8) {
          float o0 = 0.0f, o1 = 0.0f;
          #pragma unroll
          for (int s2 = 0; s2 < 7; ++s2) o0 = fmaf(lw0[s2], G[li0[s2] * GS + c], o0);
          #pragma unroll
          for (int s2 = 0; s2 < 7; ++s2) o1 = fmaf(lw1[s2], G[li1[s2] * GS + c], o1);
          asm volatile("s_waitcnt lgkmcnt(0)" ::: "memory");
          G[ln * GS + c] = o0;
          if (h2) G[i2 * GS + c] = o1;
        }
        __syncthreads();
        // G <- G * L^T : per ROW (one wave per row), in place.
        for (int r = wv8; r < NN; r += 8) {
          float o0 = 0.0f, o1 = 0.0f;
          #pragma unroll
          for (int s2 = 0; s2 < 7; ++s2) o0 = fmaf(lw0[s2], G[r * GS + li0[s2]], o0);
          #pragma unroll
          for (int s2 = 0; s2 < 7; ++s2) o1 = fmaf(lw1[s2], G[r * GS + li1[s2]], o1);
          asm volatile("s_waitcnt lgkmcnt(0)" ::: "memory");
          G[r * GS + ln] = o0;
          if (h2) G[r * GS + i2] = o1;
        }
        __syncthreads();
      }
    }

    if (hop == KHOP - 1) {
      // final gram out
      for (int e = t; e < NN * NN; e += 512) GfF[e] = G[(e / NN) * GS + (e % NN)];
      __syncthreads();
      // ---- dense L^2 into G (sparse scatter, ascending k order) ----
      if (t < NN) {
        for (int j = 0; j < NN; ++j) G[t * GS + j] = 0.0f;
        int cnt = cntS[t];
        for (int s2 = 0; s2 < cnt; ++s2) {
          float w1 = wS[t][s2]; int k = idxS[t][s2];
          int c2 = cntS[k];
          for (int t2 = 0; t2 < c2; ++t2)
            G[t * GS + idxS[k][t2]] += w1 * wS[k][t2];
        }
      }
      __syncthreads();
      // ---- W = build_graph(build_graph(L^2)) ----
      for (int rep = 0; rep < 2; ++rep) {
        if (t < NN) G[t * GS + t] = 0.0f;
        __syncthreads();
        if (t < NN) {
          float s = 0.0f;
          for (int j = 0; j < NN; ++j) s += G[t * GS + j];
          Dsh[t] = 1.0f / sqrtf(s);
        }
        __syncthreads();
        for (int e = t; e < NN * NN; e += 512) {
          int i = e / NN, j = e % NN;
          G[i * GS + j] = (Dsh[j] * G[i * GS + j]) * Dsh[i];
        }
        __syncthreads();
      }
      // M = I - 0.7*W
      for (int e = t; e < NN * NN; e += 512) {
        int i = e / NN, j = e % NN;
        G[i * GS + j] = ((i == j) ? 1.0f : 0.0f) - 0.7f * G[i * GS + j];
      }
      __syncthreads();
      // ---- Gauss-Jordan inverse: ONE barrier per k. Next pivot row/col
      // captured into ping-pong buffers during the update itself. ----
      if (t < NN) { rowkA[t] = G[t]; colkA[t] = G[t * GS]; }   // row 0 / col 0
      __syncthreads();
      {
        float* rC = rowkA; float* cC = colkA;
        float* rN = rowkB; float* cN = colkB;
        const int i0 = t / NN, j0 = t - i0 * NN;
        const int a0 = i0 * GS + j0;
        for (int k = 0; k < NN; ++k) {
          float pinv = 1.0f / rC[k];
          int i = i0, j = j0, addr = a0;
          for (int e = t; e < NN * NN; e += 512) {
            float rj = rC[j], ci = cC[i];
            float v;
            if (i == k)      v = (j == k) ? pinv : rj * pinv;
            else if (j == k) v = -(ci * pinv);
            else             v = G[addr] - ci * (rj * pinv);
            G[addr] = v;
            if (i == k + 1) rN[j] = v;      // capture next pivot row
            if (j == k + 1) cN[i] = v;      // capture next pivot col
            i += 5; j += 12; addr += 5 * GS + 12;
            if (j >= NN) { j -= NN; i += 1; addr += GS - NN; }
          }
          __syncthreads();
          float* tp;
          tp = rC; rC = rN; rN = tp;
          tp = cC; cC = cN; cN = tp;
        }
      }
      for (int e = t; e < NN * NN; e += 512) InvF[e] = G[(e / NN) * GS + (e % NN)];
    }
  }
}

// =====================================================================
// Kernel 2: 250 blocks x 512 threads, TWO episodes per block. Owner
// waves now on DIFFERENT SIMDs: ep A -> wave 0 (SIMD0), ep B -> wave 5
// (SIMD1) -- they were both on SIMD0 (wave0/wave4), serializing the two
// serial sinkhorn chains. Arithmetic unchanged.
// =====================================================================
__global__ __launch_bounds__(512) void k2_epochs(const int* __restrict__ ys,
                                                 const int* __restrict__ yq,
                                                 char* __restrict__ wsb,
                                                 float* __restrict__ out) {
  const int blk = blockIdx.x;
  const int t   = threadIdx.x;
  const int epw = t >> 8;           // half 0/1
  const int tl  = t & 255;
  const int wvl = (t >> 6) & 3;     // wave within half
  const int ln  = t & 63;
  const int b   = blk * 2 + epw;
  const float* Gq   = (const float*)(wsb + CTRL_BYTES) + (size_t)b * EP_FLT;
  const float* Invq = Gq + INV_OFF;
  unsigned* ctrlu = (unsigned*)wsb;

  __shared__ float Z[2][NN * WAYS];
  __shared__ float gvF[2][WAYS * NN];
  __shared__ float pbuf[2][4][WAYS * NN];
  __shared__ float betaS[2][WAYS][NN];
  __shared__ float nrmS[2][NN];
  __shared__ float csv[2][WAYS], pnS[2][WAYS];
  __shared__ int ysS[2][NSUP];
  __shared__ unsigned mS[2];
  __shared__ unsigned Tsh;
  __shared__ int redi[2];

  unsigned rnd = 0;

  if (tl < NSUP) ysS[epw][tl] = ys[b * NSUP + tl];
  if (tl < NN)   nrmS[epw][tl] = Gq[tl * NN + tl];
  for (int e = tl; e < WAYS * NN; e += 256) {
    int w = e / NN, n = e % NN;
    betaS[epw][w][n] = (n >= w * 5 && n < w * 5 + 5) ? 0.2f : 0.0f;
  }
  __syncthreads();

  auto sinkhorn = [&](int base, int n, float cval, bool clamp) {
    const bool own = (wvl == epw);  // ep A: wave 0 (SIMD0); ep B: wave 5 (SIMD1)
    const int r0 = ln, r1 = ln + 64;
    const bool h1 = (r1 < n);
    float p0[WAYS], p1[WAYS];
    float up0 = 0.f, up1 = 0.f, u0 = 0.f, u1 = 0.f;
    int aflag = 0;
    int m = 0; int ysq = -1;
    if (own) {
      #pragma unroll
      for (int w = 0; w < WAYS; ++w) {
        p0[w] = Z[epw][(base + r0) * WAYS + w];
        p1[w] = h1 ? Z[epw][(base + r1) * WAYS + w] : 0.f;
      }
      if (clamp && r0 < NSUP) ysq = ysS[epw][r0];
      u0 = p0[0] + p0[1] + p0[2] + p0[3] + p0[4];
      if (h1) u1 = p1[0] + p1[1] + p1[2] + p1[3] + p1[4];
      float dl = fabsf(up0 - u0);
      if (h1) dl = fmaxf(dl, fabsf(up1 - u1));
      aflag = __any(dl > 1e-3f);
    }
    unsigned target = 0;
    for (;;) {
      if (own) {
        while (m < 1000 && ((unsigned)m < target || aflag)) {
          float i0 = frcpf(u0);
          #pragma unroll
          for (int w = 0; w < WAYS; ++w) p0[w] *= i0;
          up0 = u0;
          if (h1) {
            float i1 = frcpf(u1);
            #pragma unroll
            for (int w = 0; w < WAYS; ++w) p1[w] *= i1;
            up1 = u1;
          }
          #pragma unroll
          for (int w = 0; w < WAYS; ++w) {
            float s = wsum64f_fast(p0[w] + (h1 ? p1[w] : 0.f));
            float f = cval * frcpf(s);
            p0[w] *= f;
            if (h1) p1[w] *= f;
          }
          if (clamp && r0 < NSUP) {
            #pragma unroll
            for (int w = 0; w < WAYS; ++w) p0[w] = (ysq == w) ? 1.f : 0.f;
          }
          ++m;
          u0 = p0[0] + p0[1] + p0[2] + p0[3] + p0[4];
          if (h1) u1 = p1[0] + p1[1] + p1[2] + p1[3] + p1[4];
          if ((unsigned)m >= target) {
            float dl = fabsf(up0 - u0);
            if (h1) dl = fmaxf(dl, fabsf(up1 - u1));
            aflag = __any(dl > 1e-3f);
          } else {
            aflag = 1;
          }
        }
        if (ln == 0) mS[epw] = (unsigned)m;
      }
      __syncthreads();
      if (t == 0) {
        unsigned lm = mS[0] > mS[1] ? mS[0] : mS[1];
        Tsh = grid_barrier_max(ctrlu, blk, rnd, lm);
      }
      __syncthreads();
      ++rnd;
      unsigned T = Tsh;
      if (T == target) break;
      target = T;
    }
    if (own) {
      #pragma unroll
      for (int w = 0; w < WAYS; ++w) {
        Z[epw][(base + r0) * WAYS + w] = p0[w];
        if (h1) Z[epw][(base + r1) * WAYS + w] = p1[w];
      }
    }
    __syncthreads();
  };

  for (int epi = 0; epi <= NEPOCH; ++epi) {
    // gv[w][r] = sum_k G[r][k]*beta[w][k]  (k split over 4 waves per half)
    {
      float a0[WAYS], a1[WAYS];
      #pragma unroll
      for (int w = 0; w < WAYS; ++w) { a0[w] = 0.f; a1[w] = 0.f; }
      int k0 = wvl * 25;
      for (int kk = 0; kk < 25; ++kk) {
        int k = k0 + kk;
        float g0 = Gq[(size_t)k * NN + ln];
        float g1 = (ln < NN - 64) ? Gq[(size_t)k * NN + 64 + ln] : 0.f;
        #pragma unroll
        for (int w = 0; w < WAYS; ++w) {
          float bw = betaS[epw][w][k];
          a0[w] = fmaf(g0, bw, a0[w]);
          a1[w] = fmaf(g1, bw, a1[w]);
        }
      }
      #pragma unroll
      for (int w = 0; w < WAYS; ++w) {
        pbuf[epw][wvl][w * NN + ln] = a0[w];
        if (ln < NN - 64) pbuf[epw][wvl][w * NN + 64 + ln] = a1[w];
      }
    }
    __syncthreads();
    for (int e = tl; e < WAYS * NN; e += 256)
      gvF[epw][e] = ((pbuf[epw][0][e] + pbuf[epw][1][e]) + pbuf[epw][2][e]) + pbuf[epw][3][e];
    __syncthreads();
    if (tl < WAYS) {
      float s = 0.f;
      for (int n = 0; n < NN; ++n) s = fmaf(betaS[epw][tl][n], gvF[epw][tl * NN + n], s);
      pnS[epw][tl] = s;
    }
    __syncthreads();
    for (int e = tl; e < NQ * WAYS; e += 256) {
      int r = NSUP + e / WAYS, w = e % WAYS;
      float d = (nrmS[epw][r] + pnS[epw][w]) - 2.0f * gvF[epw][w * NN + r];
      Z[epw][r * WAYS + w] = expf(-10.0f * (d > 0.f ? d : 0.f));
    }
    __syncthreads();
    sinkhorn(NSUP, NQ, 15.0f, false);

    if (epi == NEPOCH) {
      if (tl == 0) redi[epw] = 0;
      __syncthreads();
      if (tl < NQ) {
        int row = NSUP + tl;
        float bv = Z[epw][row * WAYS + 0]; int am = 0;
        #pragma unroll
        for (int w = 1; w < WAYS; ++w) {
          float v = Z[epw][row * WAYS + w];
          if (v > bv) { bv = v; am = w; }
        }
        if (am == yq[b * NQ + tl]) atomicAdd(&redi[epw], 1);
      }
      __syncthreads();
      if (tl == 0) out[b] = (float)redi[epw] / 75.0f;
    } else {
      if (tl < NSUP) {
        #pragma unroll
        for (int w = 0; w < WAYS; ++w) Z[epw][tl * WAYS + w] = (ysS[epw][tl] == w) ? 1.f : 0.f;
      }
      __syncthreads();
      for (int r = wvl; r < NN; r += 4) {
        float a0 = 0, a1 = 0, a2 = 0, a3 = 0, a4 = 0;
        for (int k = ln; k < NN; k += 64) {
          float iv = Invq[(size_t)r * NN + k];
          a0 = fmaf(iv, Z[epw][k * WAYS + 0], a0);
          a1 = fmaf(iv, Z[epw][k * WAYS + 1], a1);
          a2 = fmaf(iv, Z[epw][k * WAYS + 2], a2);
          a3 = fmaf(iv, Z[epw][k * WAYS + 3], a3);
          a4 = fmaf(iv, Z[epw][k * WAYS + 4], a4);
        }
        a0 = wsum64f_fast(a0); a1 = wsum64f_fast(a1); a2 = wsum64f_fast(a2);
        a3 = wsum64f_fast(a3); a4 = wsum64f_fast(a4);
        if (ln == 0) {
          pbuf[epw][0][r * WAYS + 0] = a0; pbuf[epw][0][r * WAYS + 1] = a1;
          pbuf[epw][0][r * WAYS + 2] = a2; pbuf[epw][0][r * WAYS + 3] = a3;
          pbuf[epw][0][r * WAYS + 4] = a4;
        }
      }
      __syncthreads();
      for (int e = tl; e < NN * WAYS; e += 256) Z[epw][e] = pbuf[epw][0][e];
      __syncthreads();
      sinkhorn(0, NN, 20.0f, true);
      if (tl < WAYS) {
        float s = 0.f;
        for (int r = 0; r < NN; ++r) s += Z[epw][r * WAYS + tl];
        csv[epw][tl] = s;
      }
      __syncthreads();
      for (int e = tl; e < NN * WAYS; e += 256) {
        int n = e / WAYS, w = e % WAYS;
        float nb = Z[epw][n * WAYS + w] / csv[epw][w];
        betaS[epw][w][n] = 0.4f * betaS[epw][w][n] + 0.6f * nb;
      }
      __syncthreads();
    }
  }
}

extern "C" void kernel_launch(void* const* d_in, const int* in_sizes, int n_in,
                              void* d_out, int out_size, void* d_ws, size_t ws_size,
                              hipStream_t stream) {
  const float* xs = (const float*)d_in[0];
  const float* xq = (const float*)d_in[1];
  const int*   ys = (const int*)d_in[2];
  const int*   yq = (const int*)d_in[3];
  float* out = (float*)d_out;
  char* ws   = (char*)d_ws;

  hipMemsetAsync(d_ws, 0, CTRL_BYTES, stream);

  (void)hipFuncSetAttribute((const void*)k1_lds,
                            hipFuncAttributeMaxDynamicSharedMemorySize,
                            DYN_LDS_BYTES);
  hipLaunchKernelGGL(k1_lds, dim3(B_RUNS), dim3(512), DYN_LDS_BYTES, stream, xs, xq, ws);
  hipLaunchKernelGGL(k2_epochs, dim3(KB2), dim3(512), 0, stream, ys, yq, ws, out);
}

// Round 9
// 1528.000 us; speedup vs baseline: 1.0918x; 1.0918x over previous
//
#include <hip/hip_runtime.h>

// ---------------- problem constants ----------------
#define B_RUNS 500
#define WAYS   5
#define NSUP   25
#define NQ     75
#define NN     100
#define DIM    640
#define TOPK   6
#define KHOP   4
#define NEPOCH 10

// ---------------- barrier control region ----------------
#define CTRL_BYTES 262144
#define KB2    250                // k2 blocks (2 episodes each)
#define NBK    25                 // buckets
#define BPB    10                 // blocks per bucket (250/25)
#define NROUND 512
#define READYB 0x80000000u

// per-episode FLOATS: Gf [10000] f32 | Inv [10000] f32
#define EP_FLT   20224
#define GF_OFF   0
#define INV_OFF  10000

// k1 LDS: G (f32, stride 101); gram staging (2 x 1616 f32 dbuf) overlaid.
#define GS   101
#define DYN_LDS_BYTES (NN * GS * 4)          // 40400 B

#if defined(__has_builtin)
#if __has_builtin(__builtin_amdgcn_permlane32_swap)
#define HAVE_PLSWAP 1
#endif
#endif

// ---------------- fast wave-64 f32 helpers ----------------
template <int CTRL>
__device__ __forceinline__ float dpp_addf(float v) {
  int r = __builtin_amdgcn_update_dpp(0, __float_as_int(v), CTRL, 0xF, 0xF, false);
  return v + __int_as_float(r);
}
template <int PAT>
__device__ __forceinline__ float swz_addf(float v) {
  return v + __int_as_float(__builtin_amdgcn_ds_swizzle(__float_as_int(v), PAT));
}
__device__ __forceinline__ float swap32_addf(float v) {
#ifdef HAVE_PLSWAP
  int x = __float_as_int(v);
  auto r = __builtin_amdgcn_permlane32_swap(x, x, false, false);
  return __int_as_float(r[0]) + __int_as_float(r[1]);
#else
  return v + __shfl_xor(v, 32, 64);
#endif
}
// full 64-lane f32 sum, result uniform across lanes
__device__ __forceinline__ float wsum64f_fast(float v) {
  v = dpp_addf<0x121>(v);    // row_ror:1
  v = dpp_addf<0x122>(v);    // row_ror:2
  v = dpp_addf<0x124>(v);    // row_ror:4
  v = dpp_addf<0x128>(v);    // row_ror:8
  v = swz_addf<0x401F>(v);   // xor 16
  v = swap32_addf(v);        // xor 32
  return __int_as_float(__builtin_amdgcn_readfirstlane(__float_as_int(v)));
}
// fast f32 reciprocal: hw rcp + 1 Newton
__device__ __forceinline__ float frcpf(float x) {
#if __has_builtin(__builtin_amdgcn_rcpf)
  float r = __builtin_amdgcn_rcpf(x);
#else
  float r = 1.0f / x;
#endif
  float e = fmaf(-x, r, 1.0f);
  r = fmaf(r, e, r);
  return r;
}

// 2-level grid barrier + global max of payload, hierarchical release.
__device__ unsigned grid_barrier_max(unsigned* ctrlu, int b, unsigned rnd, unsigned lm) {
  unsigned r = rnd < (NROUND - 1) ? rnd : (NROUND - 1);
  const int bk = b % NBK;
  unsigned* barr  = ctrlu + bk * NROUND + r;
  unsigned* bmax  = ctrlu + (NBK + bk) * NROUND + r;
  unsigned* marr  = ctrlu + 2 * NBK * NROUND + r;
  unsigned* mmax  = ctrlu + 2 * NBK * NROUND + NROUND + r;
  unsigned* bflag = ctrlu + (2 * NBK + 2) * NROUND + bk * NROUND + r;

  __hip_atomic_fetch_max(bmax, lm, __ATOMIC_RELAXED, __HIP_MEMORY_SCOPE_AGENT);
  unsigned a = __hip_atomic_fetch_add(barr, 1u, __ATOMIC_ACQ_REL, __HIP_MEMORY_SCOPE_AGENT);
  long sp = 0;
  if (a == (unsigned)(BPB - 1)) {
    unsigned bm = __hip_atomic_load(bmax, __ATOMIC_RELAXED, __HIP_MEMORY_SCOPE_AGENT);
    __hip_atomic_fetch_max(mmax, bm, __ATOMIC_RELAXED, __HIP_MEMORY_SCOPE_AGENT);
    __hip_atomic_fetch_add(marr, 1u, __ATOMIC_ACQ_REL, __HIP_MEMORY_SCOPE_AGENT);
    while (__hip_atomic_load(marr, __ATOMIC_RELAXED, __HIP_MEMORY_SCOPE_AGENT) < (unsigned)NBK) {
      __builtin_amdgcn_s_sleep(2);
      if (++sp > 50000000L) break;   // safety: terminate, don't hang
    }
    __builtin_amdgcn_fence(__ATOMIC_ACQUIRE, "agent");
    unsigned g = __hip_atomic_load(mmax, __ATOMIC_RELAXED, __HIP_MEMORY_SCOPE_AGENT);
    __hip_atomic_store(bflag, g | READYB, __ATOMIC_RELEASE, __HIP_MEMORY_SCOPE_AGENT);
    return g;
  } else {
    unsigned f;
    while (!((f = __hip_atomic_load(bflag, __ATOMIC_RELAXED, __HIP_MEMORY_SCOPE_AGENT)) & READYB)) {
      __builtin_amdgcn_s_sleep(4);
      if (++sp > 50000000L) break;   // safety: terminate, don't hang
    }
    __builtin_amdgcn_fence(__ATOMIC_ACQUIRE, "agent");
    return f & ~READYB;
  }
}

// =====================================================================
// Kernel 1 (gram-space), f32, 512 threads (8 waves). Gram: EXACT 20x25
// grid, 5x4 register tile (zero wasted FMAs vs 16x32/7x4's 30% waste),
// float4 quad-of-k staging, DOUBLE-BUFFERED (1 barrier/chunk, global
// load issued before the FMA loop -> latency hidden). Per-output k
// ascending -> bit-identical. GJ reverted to R7 form (uniform indexing,
// no divergent wrap). Everything else as the proven 865-us R7 kernel.
// =====================================================================
__global__ __launch_bounds__(512, 6) void k1_lds(const float* __restrict__ xs,
                                                 const float* __restrict__ xq,
                                                 char* __restrict__ wsb) {
  extern __shared__ float dynf[];
  float* G   = dynf;                  // 100 x 101 (padded stride)
  float* STf = dynf;                  // staging overlay (gram phase only)

  const int b = blockIdx.x;
  float* GfF  = (float*)(wsb + CTRL_BYTES) + (size_t)b * EP_FLT;
  float* InvF = GfF + INV_OFF;

  __shared__ float nsh[NN], Dsh[NN], rowk[NN], colk[NN];
  __shared__ float wS[NN][7];
  __shared__ int   idxS[NN][7];
  __shared__ int   cntS[NN];

  const int t  = threadIdx.x;

  // ---- initial gram G0 = F F^T (20x25 grid, 5x4 tile, dbuf f32x4) ----
  {
    const int tx = t % 25;            // col group 0..24
    const int ty = t / 25;            // row group 0..20 (t>=500 idle)
    const bool act = (t < 500);
    const int tyc = act ? ty : 19;
    int ia[5], ja[4];
    #pragma unroll
    for (int a = 0; a < 5; ++a) ia[a] = tyc + 20 * a;   // rows: exact partition
    #pragma unroll
    for (int c = 0; c < 4; ++c) ja[c] = tx + 25 * c;    // cols: exact partition

    float acc[5][4];
    #pragma unroll
    for (int a = 0; a < 5; ++a)
      #pragma unroll
      for (int c = 0; c < 4; ++c) acc[a][c] = 0.0f;

    const float* xsb = xs + (size_t)b * NSUP * DIM;
    const float* xqb = xq + (size_t)b * NQ * DIM;
    float* B0 = STf;                  // 4 quads x 404 floats
    float* B1 = STf + 1616;
    const int r_  = t >> 2;           // staging: 400 threads, one float4 each
    const int kq_ = t & 3;
    const bool stg = (t < 400);
    const float* srcb = stg ? ((r_ < NSUP) ? (xsb + r_ * DIM)
                                           : (xqb + (r_ - NSUP) * DIM)) : xsb;
    // prologue: stage chunk 0
    if (stg) {
      float4 v = *(const float4*)(srcb + 4 * kq_);
      *(float4*)(B0 + kq_ * 404 + 4 * r_) = v;
    }
    __syncthreads();

    #pragma unroll 1
    for (int chunk = 0; chunk < 40; ++chunk) {
      float* cur = (chunk & 1) ? B1 : B0;
      float* nxt = (chunk & 1) ? B0 : B1;
      float4 v;
      const bool more = stg && (chunk + 1 < 40);
      if (more) v = *(const float4*)(srcb + (chunk + 1) * 16 + 4 * kq_);
      #pragma unroll 1
      for (int q = 0; q < 4; ++q) {
        const float* cq = cur + q * 404;
        float4 cv[4];
        #pragma unroll
        for (int c = 0; c < 4; ++c) cv[c] = *(const float4*)(cq + 4 * ja[c]);
        #pragma unroll
        for (int a = 0; a < 5; ++a) {
          float4 rv = *(const float4*)(cq + 4 * ia[a]);
          #pragma unroll
          for (int c = 0; c < 4; ++c) {
            acc[a][c] = fmaf(rv.x, cv[c].x, acc[a][c]);
            acc[a][c] = fmaf(rv.y, cv[c].y, acc[a][c]);
            acc[a][c] = fmaf(rv.z, cv[c].z, acc[a][c]);
            acc[a][c] = fmaf(rv.w, cv[c].w, acc[a][c]);
          }
        }
      }
      if (more) *(float4*)(nxt + kq_ * 404 + 4 * r_) = v;
      __syncthreads();
    }
    // staging dead from here; G overlays it
    if (act) {
      #pragma unroll
      for (int a = 0; a < 5; ++a)
        #pragma unroll
        for (int c = 0; c < 4; ++c)
          G[ia[a] * GS + ja[c]] = acc[a][c];
    }
    __syncthreads();
  }

  for (int hop = 0; hop < KHOP; ++hop) {
    if (t < NN) nsh[t] = G[t * GS + t];
    __syncthreads();
    // ---- top-6 per row by clamped distance (ascending; ties -> lowest index) ----
    int kj[TOPK]; float ke[TOPK];
    if (t < NN) {
      unsigned long long m0 = 0ull, m1 = 0ull;
      const float nt = nsh[t];
      for (int s = 0; s < TOPK; ++s) {
        float best = 3.0e38f; int bj = 0;
        for (int j = 0; j < NN; ++j) {
          unsigned long long bit = (j < 64) ? ((m0 >> j) & 1ull) : ((m1 >> (j - 64)) & 1ull);
          if (bit) continue;
          float d = (nt + nsh[j]) - 2.0f * G[t * GS + j];
          d = d > 0.0f ? d : 0.0f;
          if (d < best) { best = d; bj = j; }     // strict <: lowest index wins ties
        }
        if (bj < 64) m0 |= 1ull << bj; else m1 |= 1ull << (bj - 64);
      }
      float s = 0.0f;
      unsigned long long mm0 = m0, mm1 = m1;
      #pragma unroll
      for (int sidx = 0; sidx < TOPK; ++sidx) {
        int j;
        if (mm0) { j = __ffsll((long long)mm0) - 1; mm0 &= mm0 - 1; }
        else     { j = 64 + __ffsll((long long)mm1) - 1; mm1 &= mm1 - 1; }
        float d = (nt + nsh[j]) - 2.0f * G[t * GS + j];
        d = d > 0.0f ? d : 0.0f;
        float e = expf(-10.0f * d);
        kj[sidx] = j; ke[sidx] = e;
        s += e;
      }
      Dsh[t] = 1.0f / sqrtf(s);
    }
    __syncthreads();
    // ---- build sparse L row: ascending index, self 0.5 folded/inserted ----
    if (t < NN) {
      int cnt = 0; bool sd = false;
      float dt = Dsh[t];
      #pragma unroll
      for (int sidx = 0; sidx < TOPK; ++sidx) {
        int j = kj[sidx];
        float lw = 0.5f * ((Dsh[j] * ke[sidx]) * dt);
        if (j == t) { lw = 0.5f + lw; sd = true; }
        else if (!sd && j > t) { idxS[t][cnt] = t; wS[t][cnt] = 0.5f; ++cnt; sd = true; }
        idxS[t][cnt] = j; wS[t][cnt] = lw; ++cnt;
      }
      if (!sd) { idxS[t][cnt] = t; wS[t][cnt] = 0.5f; ++cnt; }
      cntS[t] = cnt;
    }
    __syncthreads();

    // ---- congruence: G <- L (L G L^T) L^T, fully in-place in LDS ----
    {
      const int wv8 = t >> 6, ln = t & 63;
      const int i2 = ln + 64;
      const bool h2 = (i2 < NN);
      const int r1 = h2 ? i2 : 0;
      float lw0[7], lw1[7]; int li0[7], li1[7];
      {
        int c0 = cntS[ln];
        int c1 = h2 ? cntS[r1] : 0;
        #pragma unroll
        for (int s2 = 0; s2 < 7; ++s2) {
          lw0[s2] = (s2 < c0) ? wS[ln][s2] : 0.0f;
          li0[s2] = (s2 < c0) ? idxS[ln][s2] : 0;
          lw1[s2] = (s2 < c1) ? wS[r1][s2] : 0.0f;
          li1[s2] = (s2 < c1) ? idxS[r1][s2] : 0;
        }
      }
      #pragma unroll 1
      for (int pair = 0; pair < 2; ++pair) {
        // G <- L * G : per COLUMN (one wave per column), in place.
        for (int c = wv8; c < NN; c += 8) {
          float o0 = 0.0f, o1 = 0.0f;
          #pragma unroll
          for (int s2 = 0; s2 < 7; ++s2) o0 = fmaf(lw0[s2], G[li0[s2] * GS + c], o0);
          #pragma unroll
          for (int s2 = 0; s2 < 7; ++s2) o1 = fmaf(lw1[s2], G[li1[s2] * GS + c], o1);
          asm volatile("s_waitcnt lgkmcnt(0)" ::: "memory");
          G[ln * GS + c] = o0;
          if (h2) G[i2 * GS + c] = o1;
        }
        __syncthreads();
        // G <- G * L^T : per ROW (one wave per row), in place.
        for (int r = wv8; r < NN; r += 8) {
          float o0 = 0.0f, o1 = 0.0f;
          #pragma unroll
          for (int s2 = 0; s2 < 7; ++s2) o0 = fmaf(lw0[s2], G[r * GS + li0[s2]], o0);
          #pragma unroll
          for (int s2 = 0; s2 < 7; ++s2) o1 = fmaf(lw1[s2], G[r * GS + li1[s2]], o1);
          asm volatile("s_waitcnt lgkmcnt(0)" ::: "memory");
          G[r * GS + ln] = o0;
          if (h2) G[r * GS + i2] = o1;
        }
        __syncthreads();
      }
    }

    if (hop == KHOP - 1) {
      // final gram out
      for (int e = t; e < NN * NN; e += 512) GfF[e] = G[(e / NN) * GS + (e % NN)];
      __syncthreads();
      // ---- dense L^2 into G (sparse scatter, ascending k order) ----
      if (t < NN) {
        for (int j = 0; j < NN; ++j) G[t * GS + j] = 0.0f;
        int cnt = cntS[t];
        for (int s2 = 0; s2 < cnt; ++s2) {
          float w1 = wS[t][s2]; int k = idxS[t][s2];
          int c2 = cntS[k];
          for (int t2 = 0; t2 < c2; ++t2)
            G[t * GS + idxS[k][t2]] += w1 * wS[k][t2];
        }
      }
      __syncthreads();
      // ---- W = build_graph(build_graph(L^2)) ----
      for (int rep = 0; rep < 2; ++rep) {
        if (t < NN) G[t * GS + t] = 0.0f;
        __syncthreads();
        if (t < NN) {
          float s = 0.0f;
          for (int j = 0; j < NN; ++j) s += G[t * GS + j];
          Dsh[t] = 1.0f / sqrtf(s);
        }
        __syncthreads();
        for (int e = t; e < NN * NN; e += 512) {
          int i = e / NN, j = e % NN;
          G[i * GS + j] = (Dsh[j] * G[i * GS + j]) * Dsh[i];
        }
        __syncthreads();
      }
      // M = I - 0.7*W
      for (int e = t; e < NN * NN; e += 512) {
        int i = e / NN, j = e % NN;
        G[i * GS + j] = ((i == j) ? 1.0f : 0.0f) - 0.7f * G[i * GS + j];
      }
      __syncthreads();
      // ---- Gauss-Jordan sweep inverse in LDS (R7 form) ----
      for (int k = 0; k < NN; ++k) {
        if (t < NN) { rowk[t] = G[k * GS + t]; colk[t] = G[t * GS + k]; }
        __syncthreads();
        float pinv = 1.0f / rowk[k];
        for (int e = t; e < NN * NN; e += 512) {
          int i = e / NN, j = e % NN;
          float v;
          if (i == k)      v = (j == k) ? pinv : rowk[j] * pinv;
          else if (j == k) v = -(colk[i] * pinv);
          else             v = G[i * GS + j] - colk[i] * (rowk[j] * pinv);
          G[i * GS + j] = v;
        }
        __syncthreads();
      }
      for (int e = t; e < NN * NN; e += 512) InvF[e] = G[(e / NN) * GS + (e % NN)];
    }
  }
}

// =====================================================================
// Kernel 2: 250 blocks x 512 threads, TWO episodes per block. Owner
// waves on DIFFERENT SIMDs (ep A wave 0, ep B wave 5). Unchanged (R8).
// =====================================================================
__global__ __launch_bounds__(512) void k2_epochs(const int* __restrict__ ys,
                                                 const int* __restrict__ yq,
                                                 char* __restrict__ wsb,
                                                 float* __restrict__ out) {
  const int blk = blockIdx.x;
  const int t   = threadIdx.x;
  const int epw = t >> 8;           // half 0/1
  const int tl  = t & 255;
  const int wvl = (t >> 6) & 3;     // wave within half
  const int ln  = t & 63;
  const int b   = blk * 2 + epw;
  const float* Gq   = (const float*)(wsb + CTRL_BYTES) + (size_t)b * EP_FLT;
  const float* Invq = Gq + INV_OFF;
  unsigned* ctrlu = (unsigned*)wsb;

  __shared__ float Z[2][NN * WAYS];
  __shared__ float gvF[2][WAYS * NN];
  __shared__ float pbuf[2][4][WAYS * NN];
  __shared__ float betaS[2][WAYS][NN];
  __shared__ float nrmS[2][NN];
  __shared__ float csv[2][WAYS], pnS[2][WAYS];
  __shared__ int ysS[2][NSUP];
  __shared__ unsigned mS[2];
  __shared__ unsigned Tsh;
  __shared__ int redi[2];

  unsigned rnd = 0;

  if (tl < NSUP) ysS[epw][tl] = ys[b * NSUP + tl];
  if (tl < NN)   nrmS[epw][tl] = Gq[tl * NN + tl];
  for (int e = tl; e < WAYS * NN; e += 256) {
    int w = e / NN, n = e % NN;
    betaS[epw][w][n] = (n >= w * 5 && n < w * 5 + 5) ? 0.2f : 0.0f;
  }
  __syncthreads();

  auto sinkhorn = [&](int base, int n, float cval, bool clamp) {
    const bool own = (wvl == epw);  // ep A: wave 0 (SIMD0); ep B: wave 5 (SIMD1)
    const int r0 = ln, r1 = ln + 64;
    const bool h1 = (r1 < n);
    float p0[WAYS], p1[WAYS];
    float up0 = 0.f, up1 = 0.f, u0 = 0.f, u1 = 0.f;
    int aflag = 0;
    int m = 0; int ysq = -1;
    if (own) {
      #pragma unroll
      for (int w = 0; w < WAYS; ++w) {
        p0[w] = Z[epw][(base + r0) * WAYS + w];
        p1[w] = h1 ? Z[epw][(base + r1) * WAYS + w] : 0.f;
      }
      if (clamp && r0 < NSUP) ysq = ysS[epw][r0];
      u0 = p0[0] + p0[1] + p0[2] + p0[3] + p0[4];
      if (h1) u1 = p1[0] + p1[1] + p1[2] + p1[3] + p1[4];
      float dl = fabsf(up0 - u0);
      if (h1) dl = fmaxf(dl, fabsf(up1 - u1));
      aflag = __any(dl > 1e-3f);
    }
    unsigned target = 0;
    for (;;) {
      if (own) {
        while (m < 1000 && ((unsigned)m < target || aflag)) {
          float i0 = frcpf(u0);
          #pragma unroll
          for (int w = 0; w < WAYS; ++w) p0[w] *= i0;
          up0 = u0;
          if (h1) {
            float i1 = frcpf(u1);
            #pragma unroll
            for (int w = 0; w < WAYS; ++w) p1[w] *= i1;
            up1 = u1;
          }
          #pragma unroll
          for (int w = 0; w < WAYS; ++w) {
            float s = wsum64f_fast(p0[w] + (h1 ? p1[w] : 0.f));
            float f = cval * frcpf(s);
            p0[w] *= f;
            if (h1) p1[w] *= f;
          }
          if (clamp && r0 < NSUP) {
            #pragma unroll
            for (int w = 0; w < WAYS; ++w) p0[w] = (ysq == w) ? 1.f : 0.f;
          }
          ++m;
          u0 = p0[0] + p0[1] + p0[2] + p0[3] + p0[4];
          if (h1) u1 = p1[0] + p1[1] + p1[2] + p1[3] + p1[4];
          if ((unsigned)m >= target) {
            float dl = fabsf(up0 - u0);
            if (h1) dl = fmaxf(dl, fabsf(up1 - u1));
            aflag = __any(dl > 1e-3f);
          } else {
            aflag = 1;
          }
        }
        if (ln == 0) mS[epw] = (unsigned)m;
      }
      __syncthreads();
      if (t == 0) {
        unsigned lm = mS[0] > mS[1] ? mS[0] : mS[1];
        Tsh = grid_barrier_max(ctrlu, blk, rnd, lm);
      }
      __syncthreads();
      ++rnd;
      unsigned T = Tsh;
      if (T == target) break;
      target = T;
    }
    if (own) {
      #pragma unroll
      for (int w = 0; w < WAYS; ++w) {
        Z[epw][(base + r0) * WAYS + w] = p0[w];
        if (h1) Z[epw][(base + r1) * WAYS + w] = p1[w];
      }
    }
    __syncthreads();
  };

  for (int epi = 0; epi <= NEPOCH; ++epi) {
    // gv[w][r] = sum_k G[r][k]*beta[w][k]  (k split over 4 waves per half)
    {
      float a0[WAYS], a1[WAYS];
      #pragma unroll
      for (int w = 0; w < WAYS; ++w) { a0[w] = 0.f; a1[w] = 0.f; }
      int k0 = wvl * 25;
      for (int kk = 0; kk < 25; ++kk) {
        int k = k0 + kk;
        float g0 = Gq[(size_t)k * NN + ln];
        float g1 = (ln < NN - 64) ? Gq[(size_t)k * NN + 64 + ln] : 0.f;
        #pragma unroll
        for (int w = 0; w < WAYS; ++w) {
          float bw = betaS[epw][w][k];
          a0[w] = fmaf(g0, bw, a0[w]);
          a1[w] = fmaf(g1, bw, a1[w]);
        }
      }
      #pragma unroll
      for (int w = 0; w < WAYS; ++w) {
        pbuf[epw][wvl][w * NN + ln] = a0[w];
        if (ln < NN - 64) pbuf[epw][wvl][w * NN + 64 + ln] = a1[w];
      }
    }
    __syncthreads();
    for (int e = tl; e < WAYS * NN; e += 256)
      gvF[epw][e] = ((pbuf[epw][0][e] + pbuf[epw][1][e]) + pbuf[epw][2][e]) + pbuf[epw][3][e];
    __syncthreads();
    if (tl < WAYS) {
      float s = 0.f;
      for (int n = 0; n < NN; ++n) s = fmaf(betaS[epw][tl][n], gvF[epw][tl * NN + n], s);
      pnS[epw][tl] = s;
    }
    __syncthreads();
    for (int e = tl; e < NQ * WAYS; e += 256) {
      int r = NSUP + e / WAYS, w = e % WAYS;
      float d = (nrmS[epw][r] + pnS[epw][w]) - 2.0f * gvF[epw][w * NN + r];
      Z[epw][r * WAYS + w] = expf(-10.0f * (d > 0.f ? d : 0.f));
    }
    __syncthreads();
    sinkhorn(NSUP, NQ, 15.0f, false);

    if (epi == NEPOCH) {
      if (tl == 0) redi[epw] = 0;
      __syncthreads();
      if (tl < NQ) {
        int row = NSUP + tl;
        float bv = Z[epw][row * WAYS + 0]; int am = 0;
        #pragma unroll
        for (int w = 1; w < WAYS; ++w) {
          float v = Z[epw][row * WAYS + w];
          if (v > bv) { bv = v; am = w; }
        }
        if (am == yq[b * NQ + tl]) atomicAdd(&redi[epw], 1);
      }
      __syncthreads();
      if (tl == 0) out[b] = (float)redi[epw] / 75.0f;
    } else {
      if (tl < NSUP) {
        #pragma unroll
        for (int w = 0; w < WAYS; ++w) Z[epw][tl * WAYS + w] = (ysS[epw][tl] == w) ? 1.f : 0.f;
      }
      __syncthreads();
      for (int r = wvl; r < NN; r += 4) {
        float a0 = 0, a1 = 0, a2 = 0, a3 = 0, a4 = 0;
        for (int k = ln; k < NN; k += 64) {
          float iv = Invq[(size_t)r * NN + k];
          a0 = fmaf(iv, Z[epw][k * WAYS + 0], a0);
          a1 = fmaf(iv, Z[epw][k * WAYS + 1], a1);
          a2 = fmaf(iv, Z[epw][k * WAYS + 2], a2);
          a3 = fmaf(iv, Z[epw][k * WAYS + 3], a3);
          a4 = fmaf(iv, Z[epw][k * WAYS + 4], a4);
        }
        a0 = wsum64f_fast(a0); a1 = wsum64f_fast(a1); a2 = wsum64f_fast(a2);
        a3 = wsum64f_fast(a3); a4 = wsum64f_fast(a4);
        if (ln == 0) {
          pbuf[epw][0][r * WAYS + 0] = a0; pbuf[epw][0][r * WAYS + 1] = a1;
          pbuf[epw][0][r * WAYS + 2] = a2; pbuf[epw][0][r * WAYS + 3] = a3;
          pbuf[epw][0][r * WAYS + 4] = a4;
        }
      }
      __syncthreads();
      for (int e = tl; e < NN * WAYS; e += 256) Z[epw][e] = pbuf[epw][0][e];
      __syncthreads();
      sinkhorn(0, NN, 20.0f, true);
      if (tl < WAYS) {
        float s = 0.f;
        for (int r = 0; r < NN; ++r) s += Z[epw][r * WAYS + tl];
        csv[epw][tl] = s;
      }
      __syncthreads();
      for (int e = tl; e < NN * WAYS; e += 256) {
        int n = e / WAYS, w = e % WAYS;
        float nb = Z[epw][n * WAYS + w] / csv[epw][w];
        betaS[epw][w][n] = 0.4f * betaS[epw][w][n] + 0.6f * nb;
      }
      __syncthreads();
    }
  }
}

extern "C" void kernel_launch(void* const* d_in, const int* in_sizes, int n_in,
                              void* d_out, int out_size, void* d_ws, size_t ws_size,
                              hipStream_t stream) {
  const float* xs = (const float*)d_in[0];
  const float* xq = (const float*)d_in[1];
  const int*   ys = (const int*)d_in[2];
  const int*   yq = (const int*)d_in[3];
  float* out = (float*)d_out;
  char* ws   = (char*)d_ws;

  hipMemsetAsync(d_ws, 0, CTRL_BYTES, stream);

  (void)hipFuncSetAttribute((const void*)k1_lds,
                            hipFuncAttributeMaxDynamicSharedMemorySize,
                            DYN_LDS_BYTES);
  hipLaunchKernelGGL(k1_lds, dim3(B_RUNS), dim3(512), DYN_LDS_BYTES, stream, xs, xq, ws);
  hipLaunchKernelGGL(k2_epochs, dim3(KB2), dim3(512), 0, stream, ys, yq, ws, out);
}